// Round 1
// baseline (1418.587 us; speedup 1.0000x reference)
//
#include <hip/hip_runtime.h>

#define IMG_H 512
#define IMG_W 512
#define NIMG 16
#define NPIX (NIMG * IMG_H * IMG_W)   // 4,194,304 pixels per input
#define HW (IMG_H * IMG_W)            // 262,144
#define BINS 65536                    // LEVELS*LEVELS

// ---------------------------------------------------------------------------
// Kernel 1: gray = round(mean(channels) * 255), uint8, for both inputs.
// Mirrors JAX float32 op order: ((c0+c1+c2)/3.0f)*255.0f, round-nearest-even.
// ---------------------------------------------------------------------------
__global__ void gray_kernel(const float* __restrict__ og,
                            const float* __restrict__ gg,
                            unsigned char* __restrict__ gray_og,
                            unsigned char* __restrict__ gray_gg) {
    int idx = blockIdx.x * blockDim.x + threadIdx.x;
    if (idx >= NPIX) return;
    int n = idx >> 18;        // / HW
    int p = idx & (HW - 1);

    const float* o = og + (size_t)n * 3 * HW + p;
    float m0 = ((o[0] + o[HW] + o[2 * HW]) / 3.0f) * 255.0f;
    gray_og[idx] = (unsigned char)__float2int_rn(m0);

    const float* g = gg + (size_t)n * 3 * HW + p;
    float m1 = ((g[0] + g[HW] + g[2 * HW]) / 3.0f) * 255.0f;
    gray_gg[idx] = (unsigned char)__float2int_rn(m1);
}

// ---------------------------------------------------------------------------
// Kernel 2: raw joint-value histograms, 4 shifts per input.
// shifted[h,w] = gray[(h-dx)&511, (w-dy)&511]; joint = center*256 + shifted.
// SHIFTS = (1,0),(1,1),(0,1),(-1,1)
// blockIdx.y selects input (0 = original, 1 = generated).
// ---------------------------------------------------------------------------
__global__ void hist_kernel(const unsigned char* __restrict__ g0,
                            const unsigned char* __restrict__ g1,
                            unsigned int* __restrict__ hist) {
    int idx = blockIdx.x * blockDim.x + threadIdx.x;
    if (idx >= NPIX) return;
    const unsigned char* g = blockIdx.y ? g1 : g0;
    unsigned int* h = hist + (size_t)blockIdx.y * 4 * BINS;

    int n = idx >> 18;
    int p = idx & (HW - 1);
    int r = p >> 9;
    int c = p & 511;

    unsigned int base = ((unsigned int)g[idx]) << 8;
    const unsigned char* gn = g + (n << 18);
    int rm1 = (r - 1) & 511;
    int rp1 = (r + 1) & 511;
    int cm1 = (c - 1) & 511;

    atomicAdd(&h[0 * BINS + base + gn[(rm1 << 9) | c  ]], 1u);  // (dx,dy)=(1,0)
    atomicAdd(&h[1 * BINS + base + gn[(rm1 << 9) | cm1]], 1u);  // (1,1)
    atomicAdd(&h[2 * BINS + base + gn[(r   << 9) | cm1]], 1u);  // (0,1)
    atomicAdd(&h[3 * BINS + base + gn[(rp1 << 9) | cm1]], 1u);  // (-1,1)
}

// ---------------------------------------------------------------------------
// Kernel 3: per histogram (8 total): vmin/vmax = first/last nonzero bin,
// then contrast_a = 2 * sum_v C[v]*(i-j)^2 / 33554432 with the exact
// float32 histc remap  b = clip(floor((v-vmin)*65536/max(vmax-vmin,1)),0,65535).
// ---------------------------------------------------------------------------
__global__ void contrast_kernel(const unsigned int* __restrict__ hist,
                                double* __restrict__ contrast) {
    const unsigned int* hh = hist + (size_t)blockIdx.x * BINS;
    int t = threadIdx.x;

    __shared__ int smin[256];
    __shared__ int smax[256];
    int lmin = BINS, lmax = -1;
    for (int v = t; v < BINS; v += 256) {
        if (hh[v]) {
            if (v < lmin) lmin = v;
            if (v > lmax) lmax = v;
        }
    }
    smin[t] = lmin; smax[t] = lmax;
    __syncthreads();
    for (int s = 128; s > 0; s >>= 1) {
        if (t < s) {
            smin[t] = min(smin[t], smin[t + s]);
            smax[t] = max(smax[t], smax[t + s]);
        }
        __syncthreads();
    }
    int vmin = smin[0];
    int vmax = smax[0];
    float scale = 65536.0f / fmaxf((float)(vmax - vmin), 1.0f);

    double lsum = 0.0;
    for (int v = t; v < BINS; v += 256) {
        unsigned int cnt = hh[v];
        if (cnt) {
            int b = (int)floorf((float)(v - vmin) * scale);
            b = b < 0 ? 0 : (b > 65535 ? 65535 : b);
            int d = (b >> 8) - (b & 255);
            lsum += (double)cnt * (double)(d * d);
        }
    }
    __shared__ double sd[256];
    sd[t] = lsum;
    __syncthreads();
    for (int s = 128; s > 0; s >>= 1) {
        if (t < s) sd[t] += sd[t + s];
        __syncthreads();
    }
    if (t == 0) contrast[blockIdx.x] = 2.0 * sd[0] / 33554432.0;
}

// ---------------------------------------------------------------------------
// Kernel 4: loss = mean over 4 angles of |c_og - c_gg|
// ---------------------------------------------------------------------------
__global__ void loss_kernel(const double* __restrict__ contrast,
                            float* __restrict__ out) {
    double s = 0.0;
    for (int a = 0; a < 4; ++a)
        s += fabs(contrast[a] - contrast[4 + a]);
    out[0] = (float)(s * 0.25);
}

extern "C" void kernel_launch(void* const* d_in, const int* in_sizes, int n_in,
                              void* d_out, int out_size, void* d_ws, size_t ws_size,
                              hipStream_t stream) {
    const float* og = (const float*)d_in[0];
    const float* gg = (const float*)d_in[1];
    float* out = (float*)d_out;

    // workspace layout
    unsigned int* hist = (unsigned int*)d_ws;                       // 8*65536*4 = 2,097,152 B
    unsigned char* gray_og = (unsigned char*)d_ws + 8 * BINS * 4;   // 4,194,304 B
    unsigned char* gray_gg = gray_og + NPIX;                        // 4,194,304 B
    double* contrast = (double*)(gray_gg + NPIX);                   // offset 10,485,760 (8B aligned)

    hipMemsetAsync(hist, 0, 8 * BINS * sizeof(unsigned int), stream);

    gray_kernel<<<NPIX / 256, 256, 0, stream>>>(og, gg, gray_og, gray_gg);

    dim3 hgrid(NPIX / 256, 2);
    hist_kernel<<<hgrid, 256, 0, stream>>>(gray_og, gray_gg, hist);

    contrast_kernel<<<8, 256, 0, stream>>>(hist, contrast);

    loss_kernel<<<1, 1, 0, stream>>>(contrast, out);
}

// Round 2
// 444.411 us; speedup vs baseline: 3.1921x; 3.1921x over previous
//
#include <hip/hip_runtime.h>

#define IMG_H 512
#define IMG_W 512
#define NIMG 16
#define HW (IMG_H * IMG_W)        // 262,144
#define NPIX (NIMG * HW)          // 4,194,304 pixels per input

// ws layout:
//   u32 vmin[8]            @ 0    (combo = input*4 + shift)
//   u32 vmax[8]            @ 32
//   u64 sum[8]             @ 64
//   u8  gray_og[NPIX]      @ 128
//   u8  gray_gg[NPIX]      @ 128 + NPIX
// total ~8.4 MB

// ---------------------------------------------------------------------------
// init: min = UINT_MAX, max = 0, sums = 0 (d_ws is poisoned, never restored)
// ---------------------------------------------------------------------------
__global__ void init_kernel(unsigned int* __restrict__ vmin,
                            unsigned int* __restrict__ vmax,
                            unsigned long long* __restrict__ sum) {
    int t = threadIdx.x;
    if (t < 8) { vmin[t] = 0xFFFFFFFFu; vmax[t] = 0u; sum[t] = 0ull; }
}

// ---------------------------------------------------------------------------
// gray = round(((c0+c1+c2)/3)*255), float32 op order as JAX, RNE. ×4 vectorized.
// ---------------------------------------------------------------------------
__global__ void gray_kernel(const float4* __restrict__ og,
                            const float4* __restrict__ gg,
                            uchar4* __restrict__ gog,
                            uchar4* __restrict__ ggg) {
    int i = blockIdx.x * blockDim.x + threadIdx.x;   // float4-word index
    if (i >= NPIX / 4) return;
    int n = i >> 16;             // HW/4 = 65536 words per channel
    int p = i & 65535;

    const float4* o = og + (size_t)n * 3 * 65536 + p;
    float4 a = o[0], b = o[65536], c = o[2 * 65536];
    uchar4 r;
    r.x = (unsigned char)__float2int_rn(((a.x + b.x + c.x) / 3.0f) * 255.0f);
    r.y = (unsigned char)__float2int_rn(((a.y + b.y + c.y) / 3.0f) * 255.0f);
    r.z = (unsigned char)__float2int_rn(((a.z + b.z + c.z) / 3.0f) * 255.0f);
    r.w = (unsigned char)__float2int_rn(((a.w + b.w + c.w) / 3.0f) * 255.0f);
    gog[i] = r;

    const float4* g = gg + (size_t)n * 3 * 65536 + p;
    a = g[0]; b = g[65536]; c = g[2 * 65536];
    r.x = (unsigned char)__float2int_rn(((a.x + b.x + c.x) / 3.0f) * 255.0f);
    r.y = (unsigned char)__float2int_rn(((a.y + b.y + c.y) / 3.0f) * 255.0f);
    r.z = (unsigned char)__float2int_rn(((a.z + b.z + c.z) / 3.0f) * 255.0f);
    r.w = (unsigned char)__float2int_rn(((a.w + b.w + c.w) / 3.0f) * 255.0f);
    ggg[i] = r;
}

// ---------------------------------------------------------------------------
// per (input, shift): vmin/vmax of joint = center*256 + shifted over all pixels
// SHIFTS = (1,0),(1,1),(0,1),(-1,1); shifted[r,c] = g[(r-dx)&511,(c-dy)&511]
// ---------------------------------------------------------------------------
__global__ void minmax_kernel(const unsigned char* __restrict__ g0,
                              const unsigned char* __restrict__ g1,
                              unsigned int* __restrict__ vmin,
                              unsigned int* __restrict__ vmax) {
    const unsigned char* g = blockIdx.y ? g1 : g0;
    unsigned int lmin[4] = {0xFFFFFFFFu, 0xFFFFFFFFu, 0xFFFFFFFFu, 0xFFFFFFFFu};
    unsigned int lmax[4] = {0u, 0u, 0u, 0u};

    int stride = gridDim.x * blockDim.x;
    for (int idx = blockIdx.x * blockDim.x + threadIdx.x; idx < NPIX; idx += stride) {
        int n = idx >> 18;
        int p = idx & (HW - 1);
        int r = p >> 9, c = p & 511;
        const unsigned char* gn = g + (n << 18);
        unsigned int base = ((unsigned int)gn[p]) << 8;
        int rm1 = (r - 1) & 511, rp1 = (r + 1) & 511, cm1 = (c - 1) & 511;
        unsigned int v[4];
        v[0] = base + gn[(rm1 << 9) | c  ];
        v[1] = base + gn[(rm1 << 9) | cm1];
        v[2] = base + gn[(r   << 9) | cm1];
        v[3] = base + gn[(rp1 << 9) | cm1];
#pragma unroll
        for (int s = 0; s < 4; ++s) {
            lmin[s] = min(lmin[s], v[s]);
            lmax[s] = max(lmax[s], v[s]);
        }
    }
#pragma unroll
    for (int off = 32; off > 0; off >>= 1) {
#pragma unroll
        for (int s = 0; s < 4; ++s) {
            lmin[s] = min(lmin[s], (unsigned int)__shfl_down((int)lmin[s], off));
            lmax[s] = max(lmax[s], (unsigned int)__shfl_down((int)lmax[s], off));
        }
    }
    if ((threadIdx.x & 63) == 0) {
        int cb = blockIdx.y * 4;
#pragma unroll
        for (int s = 0; s < 4; ++s) {
            atomicMin(&vmin[cb + s], lmin[s]);
            atomicMax(&vmax[cb + s], lmax[s]);
        }
    }
}

// ---------------------------------------------------------------------------
// per (input, shift): sum over pixels of d^2 where
// b = clip(floor((joint - vmin) * (65536/max(vmax-vmin,1))), 0, 65535)  [f32]
// d = (b>>8) - (b&255)
// ---------------------------------------------------------------------------
__global__ void contrast_kernel(const unsigned char* __restrict__ g0,
                                const unsigned char* __restrict__ g1,
                                const unsigned int* __restrict__ vmin,
                                const unsigned int* __restrict__ vmax,
                                unsigned long long* __restrict__ sum) {
    int inp = blockIdx.y;
    const unsigned char* g = inp ? g1 : g0;

    unsigned int vm[4];
    float scale[4];
#pragma unroll
    for (int s = 0; s < 4; ++s) {
        vm[s] = vmin[inp * 4 + s];
        scale[s] = 65536.0f / fmaxf((float)(vmax[inp * 4 + s] - vm[s]), 1.0f);
    }

    unsigned int acc[4] = {0u, 0u, 0u, 0u};
    int stride = gridDim.x * blockDim.x;
    for (int idx = blockIdx.x * blockDim.x + threadIdx.x; idx < NPIX; idx += stride) {
        int n = idx >> 18;
        int p = idx & (HW - 1);
        int r = p >> 9, c = p & 511;
        const unsigned char* gn = g + (n << 18);
        unsigned int base = ((unsigned int)gn[p]) << 8;
        int rm1 = (r - 1) & 511, rp1 = (r + 1) & 511, cm1 = (c - 1) & 511;
        unsigned int v[4];
        v[0] = base + gn[(rm1 << 9) | c  ];
        v[1] = base + gn[(rm1 << 9) | cm1];
        v[2] = base + gn[(r   << 9) | cm1];
        v[3] = base + gn[(rp1 << 9) | cm1];
#pragma unroll
        for (int s = 0; s < 4; ++s) {
            int b = (int)floorf((float)(v[s] - vm[s]) * scale[s]);
            b = b < 0 ? 0 : (b > 65535 ? 65535 : b);
            int d = (b >> 8) - (b & 255);
            acc[s] += (unsigned int)(d * d);
        }
    }
#pragma unroll
    for (int off = 32; off > 0; off >>= 1)
#pragma unroll
        for (int s = 0; s < 4; ++s)
            acc[s] += (unsigned int)__shfl_down((int)acc[s], off);

    __shared__ unsigned int bsum[4];
    if (threadIdx.x < 4) bsum[threadIdx.x] = 0u;
    __syncthreads();
    if ((threadIdx.x & 63) == 0)
#pragma unroll
        for (int s = 0; s < 4; ++s) atomicAdd(&bsum[s], acc[s]);
    __syncthreads();
    if (threadIdx.x < 4)
        atomicAdd(&sum[inp * 4 + threadIdx.x], (unsigned long long)bsum[threadIdx.x]);
}

// ---------------------------------------------------------------------------
// loss = mean over angles of |c_og - c_gg|,  c = 2*S/33554432
// ---------------------------------------------------------------------------
__global__ void loss_kernel(const unsigned long long* __restrict__ sum,
                            float* __restrict__ out) {
    double s = 0.0;
    for (int a = 0; a < 4; ++a) {
        double co = 2.0 * (double)sum[a]     / 33554432.0;
        double cg = 2.0 * (double)sum[4 + a] / 33554432.0;
        s += fabs(co - cg);
    }
    out[0] = (float)(s * 0.25);
}

extern "C" void kernel_launch(void* const* d_in, const int* in_sizes, int n_in,
                              void* d_out, int out_size, void* d_ws, size_t ws_size,
                              hipStream_t stream) {
    const float* og = (const float*)d_in[0];
    const float* gg = (const float*)d_in[1];
    float* out = (float*)d_out;

    unsigned int* vmin = (unsigned int*)d_ws;
    unsigned int* vmax = vmin + 8;
    unsigned long long* sum = (unsigned long long*)((char*)d_ws + 64);
    unsigned char* gray_og = (unsigned char*)d_ws + 128;
    unsigned char* gray_gg = gray_og + NPIX;

    init_kernel<<<1, 32, 0, stream>>>(vmin, vmax, sum);

    gray_kernel<<<(NPIX / 4) / 256, 256, 0, stream>>>(
        (const float4*)og, (const float4*)gg, (uchar4*)gray_og, (uchar4*)gray_gg);

    dim3 mmgrid(512, 2);
    minmax_kernel<<<mmgrid, 256, 0, stream>>>(gray_og, gray_gg, vmin, vmax);

    dim3 cgrid(1024, 2);
    contrast_kernel<<<cgrid, 256, 0, stream>>>(gray_og, gray_gg, vmin, vmax, sum);

    loss_kernel<<<1, 1, 0, stream>>>(sum, out);
}

// Round 3
// 60.213 us; speedup vs baseline: 23.5594x; 7.3806x over previous
//
#include <hip/hip_runtime.h>

#define IMG_H 512
#define IMG_W 512
#define NIMG 16
#define HW (IMG_H * IMG_W)        // 262,144
#define NPIX (NIMG * HW)          // 4,194,304 pixels per input
#define SEGS_TOTAL (NPIX / 16)    // 262,144 16-pixel segments per input
#define NTHREADS 65536            // 256 blocks x 256 threads per input
#define SEGS_PER_THREAD (SEGS_TOTAL / NTHREADS)   // 4

union Bytes { uint4 v; unsigned char b[16]; };

// ---------------------------------------------------------------------------
// init: min = UINT_MAX, max = 0, sums = 0 (d_ws is poisoned, never restored)
// ---------------------------------------------------------------------------
__global__ void init_kernel(unsigned int* __restrict__ vmin,
                            unsigned int* __restrict__ vmax,
                            unsigned long long* __restrict__ sum) {
    int t = threadIdx.x;
    if (t < 8) { vmin[t] = 0xFFFFFFFFu; vmax[t] = 0u; sum[t] = 0ull; }
}

// ---------------------------------------------------------------------------
// gray = round(((c0+c1+c2)/3)*255), float32 op order as JAX, RNE. x4 vectorized.
// ---------------------------------------------------------------------------
__global__ void gray_kernel(const float4* __restrict__ og,
                            const float4* __restrict__ gg,
                            uchar4* __restrict__ gog,
                            uchar4* __restrict__ ggg) {
    int i = blockIdx.x * blockDim.x + threadIdx.x;   // float4-word index
    if (i >= NPIX / 4) return;
    int n = i >> 16;             // HW/4 = 65536 words per channel
    int p = i & 65535;

    const float4* o = og + (size_t)n * 3 * 65536 + p;
    float4 a = o[0], b = o[65536], c = o[2 * 65536];
    uchar4 r;
    r.x = (unsigned char)__float2int_rn(((a.x + b.x + c.x) / 3.0f) * 255.0f);
    r.y = (unsigned char)__float2int_rn(((a.y + b.y + c.y) / 3.0f) * 255.0f);
    r.z = (unsigned char)__float2int_rn(((a.z + b.z + c.z) / 3.0f) * 255.0f);
    r.w = (unsigned char)__float2int_rn(((a.w + b.w + c.w) / 3.0f) * 255.0f);
    gog[i] = r;

    const float4* g = gg + (size_t)n * 3 * 65536 + p;
    a = g[0]; b = g[65536]; c = g[2 * 65536];
    r.x = (unsigned char)__float2int_rn(((a.x + b.x + c.x) / 3.0f) * 255.0f);
    r.y = (unsigned char)__float2int_rn(((a.y + b.y + c.y) / 3.0f) * 255.0f);
    r.z = (unsigned char)__float2int_rn(((a.z + b.z + c.z) / 3.0f) * 255.0f);
    r.w = (unsigned char)__float2int_rn(((a.w + b.w + c.w) / 3.0f) * 255.0f);
    ggg[i] = r;
}

// ---------------------------------------------------------------------------
// Segment loader: for global segment index sidx (16 pixels of one row),
// loads rows r-1, r, r+1 (16B each, aligned) + the 3 wrap-around boundary
// bytes at column (c0-1)&511.
// SHIFTS = (1,0),(1,1),(0,1),(-1,1); shifted[r,c] = g[(r-dx)&511,(c-dy)&511]
// ---------------------------------------------------------------------------
struct Seg {
    Bytes rm, rc, rp;
    unsigned char pm, pc, pp;
};

__device__ __forceinline__ void load_seg(const unsigned char* __restrict__ g,
                                         int sidx, Seg& s) {
    int n = sidx >> 14;                 // 16384 segments per image
    int seg = sidx & 16383;
    int r = seg >> 5;                   // 32 segments per row
    int c0 = (seg & 31) << 4;
    const unsigned char* gn = g + (n << 18);
    int rm1 = (r - 1) & 511;
    int rp1 = (r + 1) & 511;
    int cprev = (c0 - 1) & 511;
    s.rm.v = *(const uint4*)(gn + (rm1 << 9) + c0);
    s.rc.v = *(const uint4*)(gn + (r   << 9) + c0);
    s.rp.v = *(const uint4*)(gn + (rp1 << 9) + c0);
    s.pm = gn[(rm1 << 9) | cprev];
    s.pc = gn[(r   << 9) | cprev];
    s.pp = gn[(rp1 << 9) | cprev];
}

// ---------------------------------------------------------------------------
// per (input, shift): vmin/vmax of joint = center*256 + shifted
// ---------------------------------------------------------------------------
__global__ void minmax_kernel(const unsigned char* __restrict__ g0,
                              const unsigned char* __restrict__ g1,
                              unsigned int* __restrict__ vmin,
                              unsigned int* __restrict__ vmax) {
    int inp = blockIdx.y;
    const unsigned char* g = inp ? g1 : g0;
    int t = blockIdx.x * blockDim.x + threadIdx.x;

    Seg s[SEGS_PER_THREAD];
#pragma unroll
    for (int k = 0; k < SEGS_PER_THREAD; ++k)
        load_seg(g, t + k * NTHREADS, s[k]);

    unsigned int lmin[4] = {0xFFFFFFFFu, 0xFFFFFFFFu, 0xFFFFFFFFu, 0xFFFFFFFFu};
    unsigned int lmax[4] = {0u, 0u, 0u, 0u};
#pragma unroll
    for (int k = 0; k < SEGS_PER_THREAD; ++k) {
#pragma unroll
        for (int j = 0; j < 16; ++j) {
            unsigned int base = ((unsigned int)s[k].rc.b[j]) << 8;
            unsigned int v0 = base + s[k].rm.b[j];
            unsigned int v1 = base + (j ? s[k].rm.b[j - 1] : s[k].pm);
            unsigned int v2 = base + (j ? s[k].rc.b[j - 1] : s[k].pc);
            unsigned int v3 = base + (j ? s[k].rp.b[j - 1] : s[k].pp);
            lmin[0] = min(lmin[0], v0); lmax[0] = max(lmax[0], v0);
            lmin[1] = min(lmin[1], v1); lmax[1] = max(lmax[1], v1);
            lmin[2] = min(lmin[2], v2); lmax[2] = max(lmax[2], v2);
            lmin[3] = min(lmin[3], v3); lmax[3] = max(lmax[3], v3);
        }
    }
#pragma unroll
    for (int off = 32; off > 0; off >>= 1) {
#pragma unroll
        for (int sh = 0; sh < 4; ++sh) {
            lmin[sh] = min(lmin[sh], (unsigned int)__shfl_down((int)lmin[sh], off));
            lmax[sh] = max(lmax[sh], (unsigned int)__shfl_down((int)lmax[sh], off));
        }
    }
    __shared__ unsigned int smin[4], smax[4];
    if (threadIdx.x < 4) { smin[threadIdx.x] = 0xFFFFFFFFu; smax[threadIdx.x] = 0u; }
    __syncthreads();
    if ((threadIdx.x & 63) == 0) {
#pragma unroll
        for (int sh = 0; sh < 4; ++sh) {
            atomicMin(&smin[sh], lmin[sh]);
            atomicMax(&smax[sh], lmax[sh]);
        }
    }
    __syncthreads();
    if (threadIdx.x < 4) {
        atomicMin(&vmin[inp * 4 + threadIdx.x], smin[threadIdx.x]);
        atomicMax(&vmax[inp * 4 + threadIdx.x], smax[threadIdx.x]);
    }
}

// ---------------------------------------------------------------------------
// per (input, shift): sum over pixels of d^2 where
// b = clip(floor((joint - vmin) * (65536/max(vmax-vmin,1))), 0, 65535)  [f32]
// d = (b>>8) - (b&255)
// ---------------------------------------------------------------------------
__global__ void contrast_kernel(const unsigned char* __restrict__ g0,
                                const unsigned char* __restrict__ g1,
                                const unsigned int* __restrict__ vmin,
                                const unsigned int* __restrict__ vmax,
                                unsigned long long* __restrict__ sum) {
    int inp = blockIdx.y;
    const unsigned char* g = inp ? g1 : g0;
    int t = blockIdx.x * blockDim.x + threadIdx.x;

    unsigned int vm[4];
    float scale[4];
#pragma unroll
    for (int sh = 0; sh < 4; ++sh) {
        vm[sh] = vmin[inp * 4 + sh];
        scale[sh] = 65536.0f / fmaxf((float)(vmax[inp * 4 + sh] - vm[sh]), 1.0f);
    }

    Seg s[SEGS_PER_THREAD];
#pragma unroll
    for (int k = 0; k < SEGS_PER_THREAD; ++k)
        load_seg(g, t + k * NTHREADS, s[k]);

    unsigned int acc[4] = {0u, 0u, 0u, 0u};
#pragma unroll
    for (int k = 0; k < SEGS_PER_THREAD; ++k) {
#pragma unroll
        for (int j = 0; j < 16; ++j) {
            unsigned int base = ((unsigned int)s[k].rc.b[j]) << 8;
            unsigned int v[4];
            v[0] = base + s[k].rm.b[j];
            v[1] = base + (j ? s[k].rm.b[j - 1] : s[k].pm);
            v[2] = base + (j ? s[k].rc.b[j - 1] : s[k].pc);
            v[3] = base + (j ? s[k].rp.b[j - 1] : s[k].pp);
#pragma unroll
            for (int sh = 0; sh < 4; ++sh) {
                int b = (int)floorf((float)(v[sh] - vm[sh]) * scale[sh]);
                b = b < 0 ? 0 : (b > 65535 ? 65535 : b);
                int d = (b >> 8) - (b & 255);
                acc[sh] += (unsigned int)(d * d);
            }
        }
    }
#pragma unroll
    for (int off = 32; off > 0; off >>= 1)
#pragma unroll
        for (int sh = 0; sh < 4; ++sh)
            acc[sh] += (unsigned int)__shfl_down((int)acc[sh], off);

    __shared__ unsigned int bsum[4];
    if (threadIdx.x < 4) bsum[threadIdx.x] = 0u;
    __syncthreads();
    if ((threadIdx.x & 63) == 0)
#pragma unroll
        for (int sh = 0; sh < 4; ++sh) atomicAdd(&bsum[sh], acc[sh]);
    __syncthreads();
    if (threadIdx.x < 4)
        atomicAdd(&sum[inp * 4 + threadIdx.x], (unsigned long long)bsum[threadIdx.x]);
}

// ---------------------------------------------------------------------------
// loss = mean over angles of |c_og - c_gg|,  c = 2*S/33554432
// ---------------------------------------------------------------------------
__global__ void loss_kernel(const unsigned long long* __restrict__ sum,
                            float* __restrict__ out) {
    double s = 0.0;
    for (int a = 0; a < 4; ++a) {
        double co = 2.0 * (double)sum[a]     / 33554432.0;
        double cg = 2.0 * (double)sum[4 + a] / 33554432.0;
        s += fabs(co - cg);
    }
    out[0] = (float)(s * 0.25);
}

extern "C" void kernel_launch(void* const* d_in, const int* in_sizes, int n_in,
                              void* d_out, int out_size, void* d_ws, size_t ws_size,
                              hipStream_t stream) {
    const float* og = (const float*)d_in[0];
    const float* gg = (const float*)d_in[1];
    float* out = (float*)d_out;

    unsigned int* vmin = (unsigned int*)d_ws;
    unsigned int* vmax = vmin + 8;
    unsigned long long* sum = (unsigned long long*)((char*)d_ws + 64);
    unsigned char* gray_og = (unsigned char*)d_ws + 128;
    unsigned char* gray_gg = gray_og + NPIX;

    init_kernel<<<1, 32, 0, stream>>>(vmin, vmax, sum);

    gray_kernel<<<(NPIX / 4) / 256, 256, 0, stream>>>(
        (const float4*)og, (const float4*)gg, (uchar4*)gray_og, (uchar4*)gray_gg);

    dim3 bygrid(NTHREADS / 256, 2);
    minmax_kernel<<<bygrid, 256, 0, stream>>>(gray_og, gray_gg, vmin, vmax);

    contrast_kernel<<<bygrid, 256, 0, stream>>>(gray_og, gray_gg, vmin, vmax, sum);

    loss_kernel<<<1, 1, 0, stream>>>(sum, out);
}